// Round 4
// baseline (25.006 us; speedup 1.0000x reference)
//
#include <hip/hip_runtime.h>

// SmartCNN round 4.
// Key idea: each conv output = relu(C(flip,o) + tap0[e1] + tap1[e2]) depends
// only on (flip, o, e1, e2) -> precompute the POST-RELU value for all 11x11
// class pairs per (flip,o) in LDS (2 x 1936 floats). Hot path per output:
// two nibble extracts + mad + one ds_read_b32 + store. 24 LDS reads/lane
// (vs 48), zero fp adds, zero fmax.
// Board is loaded cooperatively (lane q loads row q, coalesced 16B/lane),
// assembled via 2 shfl_xor, then flip-NORMALIZED once into a 64-bit nibble
// pack so extracts are a single 64-bit shift.

__device__ __forceinline__ int chmap(int e, int fv, int fh) {
    // log2-class -> scrambled channel index (matches reference unscramble)
    if (e == 0) return fv ? 0 : 1;   // empty channel (swaps with mask if fv)
    if (e == 1) return fh ? 3 : 2;   // class1/class2 swap if fh
    if (e == 2) return fh ? 2 : 3;
    return 1 + e;
}

__global__ __launch_bounds__(1024) void smartcnn_kernel(
    const float* __restrict__ x,
    const float* __restrict__ W0,
    const float* __restrict__ b0,
    const float* __restrict__ W1,
    float* __restrict__ out,
    int B)
{
    __shared__ float tabH[1936];   // [flip*4+o][e1][e2] : relu(C0 + t0h[e1] + t1h[e2])
    __shared__ float tabV[1936];   // [flip*4+o][e1][e2] : relu(C1 + t0v[e1] + t1v[e2])
    __shared__ float sW0[96], sW1[96], sb0[4];

    const int t = threadIdx.x;
    if (t < 96) { sW0[t] = W0[t]; sW1[t] = W1[t]; }
    if (t < 4)  sb0[t] = b0[t];
    __syncthreads();

#pragma unroll
    for (int it = 0; it < 2; ++it) {
        int id = t + it * 1024;
        if (id < 1936) {
            int e2 = id % 11;
            int r  = id / 11;
            int e1 = r % 11;
            int fo = r / 11;             // flip*4 + o
            int o = fo & 3, flip = fo >> 2;
            int fvv = flip >> 1, fhh = flip & 1;
            int ch1 = chmap(e1, fvv, fhh);
            int ch2 = chmap(e2, fvv, fhh);
            int mc2 = fvv ? 2 : 0;       // mask channel *2
            int o24 = o * 24;
            float C0 = sb0[o] + sW0[o24 + mc2] + sW0[o24 + mc2 + 1];
            float C1 =          sW1[o24 + mc2] + sW1[o24 + mc2 + 1];
            tabH[id] = fmaxf(C0 + sW0[o24 + ch1 * 2] + sW0[o24 + ch2 * 2 + 1], 0.0f);
            tabV[id] = fmaxf(C1 + sW1[o24 + ch1 * 2] + sW1[o24 + ch2 * 2 + 1], 0.0f);
        }
    }
    __syncthreads();

    const int gq = blockIdx.x * 1024 + t;
    const int b = gq >> 2;    // board
    const int q = gq & 3;     // quad lane: output float4 column + board row
    if (b >= B) return;

    // ---- cooperative board load: lane q loads row q (wave-contiguous) ----
    float4 row = ((const float4*)x)[(size_t)b * 4 + q];

#define EV(v) (max((int)(__float_as_uint(v) >> 23) - 127, 0))
    unsigned my = (unsigned)EV(row.x)        | ((unsigned)EV(row.y) << 4) |
                  ((unsigned)EV(row.z) << 8) | ((unsigned)EV(row.w) << 12);
#undef EV
    // assemble full board packs via quad shuffles (DPP)
    unsigned oth1 = __shfl_xor(my, 1);
    unsigned pair = (q & 1) ? ((my << 16) | oth1) : ((oth1 << 16) | my);
    unsigned oth2 = __shfl_xor(pair, 2);
    unsigned pk0 = (q & 2) ? oth2 : pair;   // rows 0,1 (row0 low)
    unsigned pk1 = (q & 2) ? pair : oth2;   // rows 2,3

    // ---- corner argmax on ORIGINAL board (classes are value-monotone) ----
    int e00 = pk0 & 15, e03 = (pk0 >> 12) & 15;
    int e30 = (pk1 >> 16) & 15, e33 = (int)(pk1 >> 28);
    int best = e00, ix = 0;
    if (e03 > best) { best = e03; ix = 1; }
    if (e30 > best) { best = e30; ix = 2; }
    if (e33 > best) { best = e33; ix = 3; }
    const int fv = ix >> 1, fh = ix & 1;

    // ---- normalize packs to the FLIPPED board ----
    unsigned fva = (pk1 >> 16) | (pk1 << 16);   // rows 3,2
    unsigned fvb = (pk0 >> 16) | (pk0 << 16);   // rows 1,0
    pk0 = fv ? fva : pk0;
    pk1 = fv ? fvb : pk1;
    unsigned ra = ((pk0 & 0x0F0F0F0Fu) << 4) | ((pk0 >> 4) & 0x0F0F0F0Fu);
    ra = ((ra & 0x00FF00FFu) << 8) | ((ra >> 8) & 0x00FF00FFu);   // nibble-reverse per row
    unsigned rb = ((pk1 & 0x0F0F0F0Fu) << 4) | ((pk1 >> 4) & 0x0F0F0F0Fu);
    rb = ((rb & 0x00FF00FFu) << 8) | ((rb >> 8) & 0x00FF00FFu);
    pk0 = fh ? ra : pk0;
    pk1 = fh ? rb : pk1;

    const unsigned long long pk = ((unsigned long long)pk1 << 32) | (unsigned long long)pk0;
#define EX(c) ((int)((pk >> ((c) * 4)) & 15ull))   // class of flipped cell c (one b64 shift)

    float4* out4 = (float4*)out + (size_t)b * 24;

#pragma unroll
    for (int rp = 0; rp < 3; ++rp) {
        int n = rp * 4 + q;           // float4 index within 48-float half
        int o = (n * 11) >> 5;        // n/3
        int s = n - 3 * o;            // sub-row 0..2
        int f1 = (s == 2) ? 1 : 0;
        int f2 = (s >= 1) ? 1 : 0;
        int s5 = s * 5;
        int base = (ix * 4 + o) * 121;

        // zh float4: cells (c, c+1)
        int c0 = s5, c1 = s5 + 1 + f1, c2 = s5 + 2 + f2, c3 = s5 + 4;
        float4 vh;
        vh.x = tabH[base + EX(c0) * 11 + EX(c0 + 1)];
        vh.y = tabH[base + EX(c1) * 11 + EX(c1 + 1)];
        vh.z = tabH[base + EX(c2) * 11 + EX(c2 + 1)];
        vh.w = tabH[base + EX(c3) * 11 + EX(c3 + 1)];
        out4[rp * 4 + q] = vh;

        // zv^T float4: cells (d, d+4)
        int d0 = s5, d1 = s5 + 4 - 11 * f1, d2 = s5 + 8 - 11 * f2, d3 = s5 + 1;
        float4 vv;
        vv.x = tabV[base + EX(d0) * 11 + EX(d0 + 4)];
        vv.y = tabV[base + EX(d1) * 11 + EX(d1 + 4)];
        vv.z = tabV[base + EX(d2) * 11 + EX(d2 + 4)];
        vv.w = tabV[base + EX(d3) * 11 + EX(d3 + 4)];
        out4[12 + rp * 4 + q] = vv;
    }
#undef EX
}

extern "C" void kernel_launch(void* const* d_in, const int* in_sizes, int n_in,
                              void* d_out, int out_size, void* d_ws, size_t ws_size,
                              hipStream_t stream) {
    const float* x  = (const float*)d_in[0];
    const float* W0 = (const float*)d_in[1];
    const float* b0 = (const float*)d_in[2];
    const float* W1 = (const float*)d_in[3];
    float* out = (float*)d_out;

    int B = in_sizes[0] / 16;
    int total = B * 4;                       // 4 lanes per board
    int blocks = (total + 1023) / 1024;
    smartcnn_kernel<<<blocks, 1024, 0, stream>>>(x, W0, b0, W1, out, B);
}